// Round 1
// baseline (277.828 us; speedup 1.0000x reference)
//
#include <hip/hip_runtime.h>

// Attention_86423331930517 — MI355X bf16-MFMA implementation.
// B=16, H=W=64, C=512, HW=4096, P=1024 pooled pixels, D=64 (qk dim), DV=256 (v dim).

#define DEVI static __device__ __forceinline__

typedef float f32x4 __attribute__((ext_vector_type(4)));
typedef short bf16x8 __attribute__((ext_vector_type(8)));

DEVI short f2bf(float f) {
  union { float f; unsigned u; } v; v.f = f;
  unsigned r = v.u + 0x7FFFu + ((v.u >> 16) & 1u);   // RNE
  return (short)(r >> 16);
}

DEVI f32x4 mfma16(bf16x8 a, bf16x8 b, f32x4 c) {
  return __builtin_amdgcn_mfma_f32_16x16x32_bf16(a, b, c, 0, 0, 0);
}

// ---------------- pooling: x[16,64,64,512] f32 -> xp[16,1024,512] bf16 ----------------
__global__ __launch_bounds__(256) void pool_kernel(const float* __restrict__ x,
                                                   short* __restrict__ xp) {
  long i = (long)blockIdx.x * 256 + threadIdx.x;   // one thread per 4 channels
  int cg = (int)(i & 127);
  int p  = (int)((i >> 7) & 1023);
  int b  = (int)(i >> 17);
  int pi = p >> 5, pj = p & 31;
  const float* base = x + ((long)((b*64 + pi*2) * 64 + pj*2) * 512) + cg*4;
  float4 a0 = *(const float4*)(base);
  float4 a1 = *(const float4*)(base + 512);
  float4 a2 = *(const float4*)(base + 64*512);
  float4 a3 = *(const float4*)(base + 64*512 + 512);
  short4 o;
  o.x = f2bf(0.25f*(a0.x+a1.x+a2.x+a3.x));
  o.y = f2bf(0.25f*(a0.y+a1.y+a2.y+a3.y));
  o.z = f2bf(0.25f*(a0.z+a1.z+a2.z+a3.z));
  o.w = f2bf(0.25f*(a0.w+a1.w+a2.w+a3.w));
  *(short4*)(xp + i*4) = o;
}

// ---------------- weights: cast to bf16 and transpose so B-operand rows are k-contiguous
__global__ __launch_bounds__(256) void prep_weights(
    const float* __restrict__ Wf, const float* __restrict__ Wg,
    const float* __restrict__ Wh, const float* __restrict__ Wo,
    short* __restrict__ WfT, short* __restrict__ WgT,
    short* __restrict__ WhT, short* __restrict__ WoT) {
  int i = blockIdx.x * 256 + threadIdx.x;   // 0..393215 exactly
  const float* src; short* dst; int K, N, e;
  if (i < 32768)       { src = Wf; dst = WfT; K = 512; N = 64;  e = i; }
  else if (i < 65536)  { src = Wg; dst = WgT; K = 512; N = 64;  e = i - 32768; }
  else if (i < 196608) { src = Wh; dst = WhT; K = 512; N = 256; e = i - 65536; }
  else                 { src = Wo; dst = WoT; K = 256; N = 512; e = i - 196608; }
  int n = e / K, k = e - n * K;            // dst[n][k] = src[k][n]
  dst[e] = f2bf(src[(long)k * N + n]);
}

// ---------------- staging helper: tile of `rows` x 64 bf16 into XOR-swizzled LDS -------
// LDS layout: byte = row*128 + ((slot ^ (row&7))<<4), slot = k/8. Reader uses same XOR.
template<bool SRC_F32>
DEVI void stage64(short* lds, const void* gsrc, int rows, int stride, int tid) {
  const int chunks = rows * 8;
  for (int c = tid; c < chunks; c += 256) {
    int row = c >> 3, slot = c & 7;
    int dstb = row*128 + ((slot ^ (row & 7)) << 4);
    bf16x8 v;
    if (SRC_F32) {
      const float* s = (const float*)gsrc + (long)row*stride + slot*8;
      float4 u0 = *(const float4*)s;
      float4 u1 = *(const float4*)(s + 4);
      v[0]=f2bf(u0.x); v[1]=f2bf(u0.y); v[2]=f2bf(u0.z); v[3]=f2bf(u0.w);
      v[4]=f2bf(u1.x); v[5]=f2bf(u1.y); v[6]=f2bf(u1.z); v[7]=f2bf(u1.w);
    } else {
      v = *(const bf16x8*)((const short*)gsrc + (long)row*stride + slot*8);
    }
    *(bf16x8*)((char*)lds + dstb) = v;
  }
}

// ---------------- generic K=512 GEMM: C[M,Nfull] = A[M,512] @ BT[N,512]^T (bf16 out) ---
// grid = (M/128, N/64), block = 256 (4 waves in 2x2), tile 128x64, BK=64.
template<bool A_F32>
__global__ __launch_bounds__(256) void gemm_k512(const void* __restrict__ A,
    const short* __restrict__ BT, short* __restrict__ C, int Nfull) {
  __shared__ short As[128*64];
  __shared__ short Bs[64*64];
  const int m0 = blockIdx.x * 128;
  const int n0 = blockIdx.y * 64;
  const int tid = threadIdx.x, w = tid >> 6, lane = tid & 63;
  const int l15 = lane & 15, lhi = lane >> 4;
  const int wr = w >> 1, wc = w & 1;
  f32x4 acc[4][2] = {};
  for (int kt = 0; kt < 8; ++kt) {
    const int k0 = kt * 64;
    if constexpr (A_F32)
      stage64<true >(As, (const float*)A + (long)m0*512 + k0, 128, 512, tid);
    else
      stage64<false>(As, (const short*)A + (long)m0*512 + k0, 128, 512, tid);
    stage64<false>(Bs, BT + (long)n0*512 + k0, 64, 512, tid);
    __syncthreads();
    bf16x8 af[4][2], bfr[2][2];
    #pragma unroll
    for (int mi = 0; mi < 4; ++mi)
      #pragma unroll
      for (int ks = 0; ks < 2; ++ks) {
        int m = wr*64 + mi*16 + l15;
        int slot = lhi + ks*4;
        af[mi][ks] = *(const bf16x8*)((const char*)As + m*128 + ((slot ^ (m & 7)) << 4));
      }
    #pragma unroll
    for (int ni = 0; ni < 2; ++ni)
      #pragma unroll
      for (int ks = 0; ks < 2; ++ks) {
        int n = wc*32 + ni*16 + l15;
        int slot = lhi + ks*4;
        bfr[ni][ks] = *(const bf16x8*)((const char*)Bs + n*128 + ((slot ^ (n & 7)) << 4));
      }
    #pragma unroll
    for (int ks = 0; ks < 2; ++ks)
      #pragma unroll
      for (int mi = 0; mi < 4; ++mi)
        #pragma unroll
        for (int ni = 0; ni < 2; ++ni)
          acc[mi][ni] = mfma16(af[mi][ks], bfr[ni][ks], acc[mi][ni]);
    __syncthreads();
  }
  #pragma unroll
  for (int mi = 0; mi < 4; ++mi)
    #pragma unroll
    for (int ni = 0; ni < 2; ++ni)
      #pragma unroll
      for (int r = 0; r < 4; ++r) {
        long row = m0 + wr*64 + mi*16 + lhi*4 + r;
        int col = n0 + wc*32 + ni*16 + l15;
        C[row * (long)Nfull + col] = f2bf(acc[mi][ni][r]);
      }
}

// ---------------- h[16*1024,256] -> hT[16*256,1024] (bf16 transpose) -------------------
__global__ __launch_bounds__(256) void transpose_h(const short* __restrict__ h,
                                                   short* __restrict__ hT) {
  __shared__ short t[64][72];                        // 144B rows: 16B aligned, odd bank stride
  const int k0 = blockIdx.x * 64, n0 = blockIdx.y * 64, b = blockIdx.z;
  const int tid = threadIdx.x;
  {
    int row = tid >> 2, cch = (tid & 3) * 16;
    const short* src = h + ((long)b*1024 + k0 + row) * 256 + n0 + cch;
    *(bf16x8*)&t[row][cch]     = *(const bf16x8*)src;
    *(bf16x8*)&t[row][cch + 8] = *(const bf16x8*)(src + 8);
  }
  __syncthreads();
  {
    int n = tid >> 2, kch = (tid & 3) * 16;
    bf16x8 lo, hi;
    #pragma unroll
    for (int j = 0; j < 8; ++j) { lo[j] = t[kch + j][n]; hi[j] = t[kch + 8 + j][n]; }
    short* dst = hT + ((long)b*256 + n0 + n) * 1024 + k0 + kch;
    *(bf16x8*)dst       = lo;
    *(bf16x8*)(dst + 8) = hi;
  }
}

// ---------------- fused attention: per block = (batch, 64 q rows) x all 1024 keys ------
// S = f@g^T (no max-subtract softmax: logits bounded ~|5|), P=exp(S) to per-wave LDS,
// y_acc += P@hT, row sums deferred; normalize at end. Wave w owns q rows w*16..w*16+15.
__global__ __launch_bounds__(256) void attn_kernel(const short* __restrict__ f,
    const short* __restrict__ g, const short* __restrict__ hT, short* __restrict__ y) {
  __shared__ short gs[64*64];      // 8KB  keys x d, swizzled
  __shared__ short hTs[256*64];    // 32KB n x keys, swizzled
  __shared__ short Ps[4*16*64];    // 8KB  per-wave P strips, swizzled
  const int b = blockIdx.y, q0 = blockIdx.x * 64;
  const int tid = threadIdx.x, w = tid >> 6, lane = tid & 63;
  const int l15 = lane & 15, lhi = lane >> 4;
  bf16x8 fq[2];
  {
    const short* frow = f + ((long)b*4096 + q0 + w*16 + l15) * 64;
    fq[0] = *(const bf16x8*)(frow + lhi*8);
    fq[1] = *(const bf16x8*)(frow + 32 + lhi*8);
  }
  f32x4 acc[16] = {};
  float rs[4] = {0.f, 0.f, 0.f, 0.f};
  short* Pw = Ps + w * 1024;
  for (int kt = 0; kt < 16; ++kt) {
    const int k0 = kt * 64;
    stage64<false>(gs,  g  + ((long)b*1024 + k0) * 64, 64, 64, tid);
    stage64<false>(hTs, hT + (long)b*256*1024 + k0,   256, 1024, tid);
    __syncthreads();
    #pragma unroll
    for (int kc = 0; kc < 4; ++kc) {
      f32x4 s = {};
      #pragma unroll
      for (int ks = 0; ks < 2; ++ks) {
        int key = kc*16 + l15;
        int slot = lhi + ks*4;
        bf16x8 gb = *(const bf16x8*)((const char*)gs + key*128 + ((slot ^ (key & 7)) << 4));
        s = mfma16(fq[ks], gb, s);
      }
      #pragma unroll
      for (int r = 0; r < 4; ++r) {
        float p = __expf(s[r]);
        rs[r] += p;
        int lq = lhi*4 + r;
        int key = kc*16 + l15;
        *(short*)((char*)Pw + ((lq*128 + key*2) ^ ((lq & 7) << 4))) = f2bf(p);
      }
    }
    asm volatile("s_waitcnt lgkmcnt(0)" ::: "memory");
    __builtin_amdgcn_sched_barrier(0);
    #pragma unroll
    for (int step = 0; step < 2; ++step) {
      bf16x8 pa = *(const bf16x8*)((const char*)Pw + l15*128 +
                                   (((lhi + step*4) ^ (l15 & 7)) << 4));
      #pragma unroll
      for (int nc = 0; nc < 16; ++nc) {
        int n = nc*16 + l15;
        bf16x8 hb = *(const bf16x8*)((const char*)hTs + n*128 +
                                     (((lhi + step*4) ^ (n & 7)) << 4));
        acc[nc] = mfma16(pa, hb, acc[nc]);
      }
    }
    __syncthreads();
  }
  #pragma unroll
  for (int r = 0; r < 4; ++r) {
    rs[r] += __shfl_xor(rs[r], 1);
    rs[r] += __shfl_xor(rs[r], 2);
    rs[r] += __shfl_xor(rs[r], 4);
    rs[r] += __shfl_xor(rs[r], 8);
    rs[r] = 1.f / rs[r];
  }
  #pragma unroll
  for (int nc = 0; nc < 16; ++nc)
    #pragma unroll
    for (int r = 0; r < 4; ++r) {
      long row = (long)b*4096 + q0 + w*16 + lhi*4 + r;
      y[row*256 + nc*16 + l15] = f2bf(acc[nc][r] * rs[r]);
    }
}

// ---------------- out = y[65536,256] @ WoT[512,256]^T + x (f32 out) --------------------
// grid = (512, 4), tile 128x128, BK=64, 4 waves in 2x2 each 64x64.
__global__ __launch_bounds__(256) void gemm_out(const short* __restrict__ y,
    const short* __restrict__ WoT, const float* __restrict__ x, float* __restrict__ out) {
  __shared__ short As[128*64];
  __shared__ short Bs[128*64];
  const int m0 = blockIdx.x * 128, n0 = blockIdx.y * 128;
  const int tid = threadIdx.x, w = tid >> 6, lane = tid & 63;
  const int l15 = lane & 15, lhi = lane >> 4;
  const int wr = w >> 1, wc = w & 1;
  f32x4 acc[4][4] = {};
  for (int kt = 0; kt < 4; ++kt) {
    const int k0 = kt * 64;
    stage64<false>(As, y   + (long)m0*256 + k0, 128, 256, tid);
    stage64<false>(Bs, WoT + (long)n0*256 + k0, 128, 256, tid);
    __syncthreads();
    bf16x8 af[4][2], bfr[4][2];
    #pragma unroll
    for (int mi = 0; mi < 4; ++mi)
      #pragma unroll
      for (int ks = 0; ks < 2; ++ks) {
        int m = wr*64 + mi*16 + l15;
        int slot = lhi + ks*4;
        af[mi][ks] = *(const bf16x8*)((const char*)As + m*128 + ((slot ^ (m & 7)) << 4));
      }
    #pragma unroll
    for (int ni = 0; ni < 4; ++ni)
      #pragma unroll
      for (int ks = 0; ks < 2; ++ks) {
        int n = wc*64 + ni*16 + l15;
        int slot = lhi + ks*4;
        bfr[ni][ks] = *(const bf16x8*)((const char*)Bs + n*128 + ((slot ^ (n & 7)) << 4));
      }
    #pragma unroll
    for (int ks = 0; ks < 2; ++ks)
      #pragma unroll
      for (int mi = 0; mi < 4; ++mi)
        #pragma unroll
        for (int ni = 0; ni < 4; ++ni)
          acc[mi][ni] = mfma16(af[mi][ks], bfr[ni][ks], acc[mi][ni]);
    __syncthreads();
  }
  #pragma unroll
  for (int mi = 0; mi < 4; ++mi)
    #pragma unroll
    for (int ni = 0; ni < 4; ++ni)
      #pragma unroll
      for (int r = 0; r < 4; ++r) {
        long row = m0 + wr*64 + mi*16 + lhi*4 + r;
        long col = n0 + wc*64 + ni*16 + l15;
        long idx = row*512 + col;
        out[idx] = acc[mi][ni][r] + x[idx];
      }
}

extern "C" void kernel_launch(void* const* d_in, const int* in_sizes, int n_in,
                              void* d_out, int out_size, void* d_ws, size_t ws_size,
                              hipStream_t stream) {
  const float* x  = (const float*)d_in[0];
  const float* Wf = (const float*)d_in[1];
  const float* Wg = (const float*)d_in[2];
  const float* Wh = (const float*)d_in[3];
  const float* Wo = (const float*)d_in[4];
  float* out = (float*)d_out;

  // workspace carve-up (bf16 elements), total ~78.2 MB
  short* xp  = (short*)d_ws;                    // [16*1024, 512]
  short* fb  = xp  + (long)16*1024*512;         // [65536, 64]
  short* gb  = fb  + (long)65536*64;            // [16384, 64]
  short* hb  = gb  + (long)16384*64;            // [16384, 256]
  short* hTb = hb  + (long)16384*256;           // [16*256, 1024]
  short* yb  = hTb + (long)16*256*1024;         // [65536, 256]
  short* WfT = yb  + (long)65536*256;           // [64, 512]
  short* WgT = WfT + 64*512;                    // [64, 512]
  short* WhT = WgT + 64*512;                    // [256, 512]
  short* WoT = WhT + 256*512;                   // [512, 256]

  pool_kernel <<<8192, 256, 0, stream>>>(x, xp);
  prep_weights<<<1536, 256, 0, stream>>>(Wf, Wg, Wh, Wo, WfT, WgT, WhT, WoT);
  gemm_k512<true ><<<dim3(512, 1), 256, 0, stream>>>((const void*)x,  WfT, fb, 64);
  gemm_k512<false><<<dim3(128, 1), 256, 0, stream>>>((const void*)xp, WgT, gb, 64);
  gemm_k512<false><<<dim3(128, 4), 256, 0, stream>>>((const void*)xp, WhT, hb, 256);
  transpose_h <<<dim3(16, 4, 16), 256, 0, stream>>>(hb, hTb);
  attn_kernel <<<dim3(64, 16),    256, 0, stream>>>(fb, gb, hTb, yb);
  gemm_out    <<<dim3(512, 4),    256, 0, stream>>>(yb, WoT, x, out);
}

// Round 2
// 211.464 us; speedup vs baseline: 1.3138x; 1.3138x over previous
//
#include <hip/hip_runtime.h>

// Attention_86423331930517 — MI355X bf16-MFMA implementation, round 2.
// B=16, H=W=64, C=512, HW=4096, P=1024 pooled pixels, D=64 (qk dim), DV=256 (v dim).

#define DEVI static __device__ __forceinline__

typedef float f32x4  __attribute__((ext_vector_type(4)));
typedef float f32x16 __attribute__((ext_vector_type(16)));
typedef short bf16x8 __attribute__((ext_vector_type(8)));

DEVI short f2bf(float f) {
  union { float f; unsigned u; } v; v.f = f;
  unsigned r = v.u + 0x7FFFu + ((v.u >> 16) & 1u);   // RNE
  return (short)(r >> 16);
}
DEVI float b2f(short s) {
  union { unsigned u; float f; } v; v.u = ((unsigned)(unsigned short)s) << 16; return v.f;
}
DEVI unsigned pack2(float a, float b) {
  return (unsigned)(unsigned short)f2bf(a) | ((unsigned)(unsigned short)f2bf(b) << 16);
}
DEVI f32x4 mfma16(bf16x8 a, bf16x8 b, f32x4 c) {
  return __builtin_amdgcn_mfma_f32_16x16x32_bf16(a, b, c, 0, 0, 0);
}
DEVI f32x16 mfma32(bf16x8 a, bf16x8 b, f32x16 c) {
  return __builtin_amdgcn_mfma_f32_32x32x16_bf16(a, b, c, 0, 0, 0);
}
DEVI void gload16(const short* gsrc, short* lds) {
  __builtin_amdgcn_global_load_lds(
      (const __attribute__((address_space(1))) void*)gsrc,
      (__attribute__((address_space(3))) void*)lds, 16, 0, 0);
}

// ---------------- weights: cast to bf16 and transpose so B-operand rows are k-contiguous
__global__ __launch_bounds__(256) void prep_weights(
    const float* __restrict__ Wf, const float* __restrict__ Wg,
    const float* __restrict__ Wh, const float* __restrict__ Wo,
    short* __restrict__ WfT, short* __restrict__ WgT,
    short* __restrict__ WhT, short* __restrict__ WoT) {
  int i = blockIdx.x * 256 + threadIdx.x;   // 0..393215 exactly
  const float* src; short* dst; int K, N, e;
  if (i < 32768)       { src = Wf; dst = WfT; K = 512; N = 64;  e = i; }
  else if (i < 65536)  { src = Wg; dst = WgT; K = 512; N = 64;  e = i - 32768; }
  else if (i < 196608) { src = Wh; dst = WhT; K = 512; N = 256; e = i - 65536; }
  else                 { src = Wo; dst = WoT; K = 256; N = 512; e = i - 196608; }
  int n = e / K, k = e - n * K;            // dst[n][k] = src[k][n]
  dst[e] = f2bf(src[(long)k * N + n]);
}

// ---------------- staging helper: tile of `rows` x 64 bf16 into XOR-swizzled LDS -------
// LDS layout: byte = row*128 + ((slot ^ (row&7))<<4), slot = k/8. Reader uses same XOR.
template<bool SRC_F32>
DEVI void stage64(short* lds, const void* gsrc, int rows, int stride, int tid) {
  const int chunks = rows * 8;
  for (int c = tid; c < chunks; c += 256) {
    int row = c >> 3, slot = c & 7;
    int dstb = row*128 + ((slot ^ (row & 7)) << 4);
    bf16x8 v;
    if (SRC_F32) {
      const float* s = (const float*)gsrc + (long)row*stride + slot*8;
      float4 u0 = *(const float4*)s;
      float4 u1 = *(const float4*)(s + 4);
      v[0]=f2bf(u0.x); v[1]=f2bf(u0.y); v[2]=f2bf(u0.z); v[3]=f2bf(u0.w);
      v[4]=f2bf(u1.x); v[5]=f2bf(u1.y); v[6]=f2bf(u1.z); v[7]=f2bf(u1.w);
    } else {
      v = *(const bf16x8*)((const short*)gsrc + (long)row*stride + slot*8);
    }
    *(bf16x8*)((char*)lds + dstb) = v;
  }
}

// ---------------- generic K=512 GEMM: C[M,Nfull] = A[M,512] @ BT[N,512]^T (bf16 out) ---
// grid = (M/128, N/64), block = 256 (4 waves in 2x2), tile 128x64, BK=64.
// POOL: the f-GEMM's 128-row A tile = pixel rows (b,h0,w*) and (b,h0+1,w*) — compute the
// 2x2-pooled xp tile (32 rows x 64 ch per k-step) from the staged LDS tile for free.
template<bool A_F32, bool POOL>
__global__ __launch_bounds__(256) void gemm_k512(const void* __restrict__ A,
    const short* __restrict__ BT, short* __restrict__ C, int Nfull,
    short* __restrict__ xp) {
  __shared__ short As[128*64];
  __shared__ short Bs[64*64];
  const int m0 = blockIdx.x * 128;
  const int n0 = blockIdx.y * 64;
  const int tid = threadIdx.x, w = tid >> 6, lane = tid & 63;
  const int l15 = lane & 15, lhi = lane >> 4;
  const int wr = w >> 1, wc = w & 1;
  f32x4 acc[4][2] = {};
  for (int kt = 0; kt < 8; ++kt) {
    const int k0 = kt * 64;
    if constexpr (A_F32)
      stage64<true >(As, (const float*)A + (long)m0*512 + k0, 128, 512, tid);
    else
      stage64<false>(As, (const short*)A + (long)m0*512 + k0, 128, 512, tid);
    stage64<false>(Bs, BT + (long)n0*512 + k0, 64, 512, tid);
    __syncthreads();
    if constexpr (POOL) {
      // pooled rows: pr0 = b*1024 + (h0/2)*32, 32 w' positions x 64 ch this k-step
      const long pr0 = (long)(m0 >> 12)*1024 + ((m0 & 4095) >> 7)*32;
      int wp = tid >> 3, cs = tid & 7;
      const char* Ab = (const char*)As;
      bf16x8 v00 = *(const bf16x8*)(Ab + (2*wp  )*128 + ((cs ^ ((2*wp  )&7))<<4));
      bf16x8 v01 = *(const bf16x8*)(Ab + (2*wp+1)*128 + ((cs ^ ((2*wp+1)&7))<<4));
      bf16x8 v10 = *(const bf16x8*)(Ab + (64+2*wp)*128 + ((cs ^ ((2*wp  )&7))<<4));
      bf16x8 v11 = *(const bf16x8*)(Ab + (65+2*wp)*128 + ((cs ^ ((2*wp+1)&7))<<4));
      bf16x8 o;
      #pragma unroll
      for (int j = 0; j < 8; ++j)
        o[j] = f2bf(0.25f*(b2f(v00[j])+b2f(v01[j])+b2f(v10[j])+b2f(v11[j])));
      *(bf16x8*)(xp + (pr0 + wp)*512 + k0 + cs*8) = o;
    }
    bf16x8 af[4][2], bfr[2][2];
    #pragma unroll
    for (int mi = 0; mi < 4; ++mi)
      #pragma unroll
      for (int ks = 0; ks < 2; ++ks) {
        int m = wr*64 + mi*16 + l15;
        int slot = lhi + ks*4;
        af[mi][ks] = *(const bf16x8*)((const char*)As + m*128 + ((slot ^ (m & 7)) << 4));
      }
    #pragma unroll
    for (int ni = 0; ni < 2; ++ni)
      #pragma unroll
      for (int ks = 0; ks < 2; ++ks) {
        int n = wc*32 + ni*16 + l15;
        int slot = lhi + ks*4;
        bfr[ni][ks] = *(const bf16x8*)((const char*)Bs + n*128 + ((slot ^ (n & 7)) << 4));
      }
    #pragma unroll
    for (int ks = 0; ks < 2; ++ks)
      #pragma unroll
      for (int mi = 0; mi < 4; ++mi)
        #pragma unroll
        for (int ni = 0; ni < 2; ++ni)
          acc[mi][ni] = mfma16(af[mi][ks], bfr[ni][ks], acc[mi][ni]);
    __syncthreads();
  }
  #pragma unroll
  for (int mi = 0; mi < 4; ++mi)
    #pragma unroll
    for (int ni = 0; ni < 2; ++ni)
      #pragma unroll
      for (int r = 0; r < 4; ++r) {
        long row = m0 + wr*64 + mi*16 + lhi*4 + r;
        int col = n0 + wc*32 + ni*16 + l15;
        C[row * (long)Nfull + col] = f2bf(acc[mi][ni][r]);
      }
}

// ---------------- h[16*1024,256] -> hT[16*256,1024] (bf16 transpose) -------------------
__global__ __launch_bounds__(256) void transpose_h(const short* __restrict__ h,
                                                   short* __restrict__ hT) {
  __shared__ short t[64][72];
  const int k0 = blockIdx.x * 64, n0 = blockIdx.y * 64, b = blockIdx.z;
  const int tid = threadIdx.x;
  {
    int row = tid >> 2, cch = (tid & 3) * 16;
    const short* src = h + ((long)b*1024 + k0 + row) * 256 + n0 + cch;
    *(bf16x8*)&t[row][cch]     = *(const bf16x8*)src;
    *(bf16x8*)&t[row][cch + 8] = *(const bf16x8*)(src + 8);
  }
  __syncthreads();
  {
    int n = tid >> 2, kch = (tid & 3) * 16;
    bf16x8 lo, hi;
    #pragma unroll
    for (int j = 0; j < 8; ++j) { lo[j] = t[kch + j][n]; hi[j] = t[kch + 8 + j][n]; }
    short* dst = hT + ((long)b*256 + n0 + n) * 1024 + k0 + kch;
    *(bf16x8*)dst       = lo;
    *(bf16x8*)(dst + 8) = hi;
  }
}

// ---------------- fused attention, 32x32x16 MFMA, QBLK=256, 8 waves -------------------
// Swapped QK^T: S = mfma(g, f) -> lane holds keys for q=lane&31 (packed b64 P-writes,
// row-sum lane-local). Swapped PV: y = mfma(hT, P) -> lane holds n-quads for q=lane&31
// (packed b64 y-writes, single-scalar normalize). 2-phase global_load_lds pipeline,
// double-buffered K/V tiles, one barrier per K-step. Dynamic LDS 112KB, 1 block/CU.
__global__ __launch_bounds__(512, 2) void attn_kernel(const short* __restrict__ f,
    const short* __restrict__ g, const short* __restrict__ hT, short* __restrict__ y) {
  extern __shared__ __align__(16) char smem[];
  // carve: gs[2] 8KB each, hTs[2] 32KB each, Ps 8 waves x 4KB
  const int b = blockIdx.y, q0 = blockIdx.x * 256;
  const int tid = threadIdx.x, w = tid >> 6, lane = tid & 63;
  const int l31 = lane & 31, hi = lane >> 5;

  short* Pw = (short*)(smem + 81920 + w*4096);   // per-wave P strip [32 q][64 keys]

  // f fragments: B-operand, col=q=l31, k = ks*16 + hi*8 + j
  bf16x8 fq[4];
  {
    const short* frow = f + ((long)b*4096 + q0 + w*32 + l31) * 64;
    #pragma unroll
    for (int ks = 0; ks < 4; ++ks) fq[ks] = *(const bf16x8*)(frow + ks*16 + hi*8);
  }

  f32x16 acc2[8] = {};     // [nc2] : n = nc2*32 + (r&3)+8*(r>>2)+4*hi, q = l31
  float rsq = 0.f;

  auto stage = [&](int buf, int kt) {
    const int k0 = kt * 64;
    short* gbuf = (short*)(smem + buf*8192);
    short* hbuf = (short*)(smem + 16384 + buf*32768);
    {
      int row = (w << 3) + (lane >> 3);
      int gslot = (lane & 7) ^ (row & 7);
      gload16(g + ((long)b*1024 + k0 + row)*64 + gslot*8, gbuf + w*512);
    }
    #pragma unroll
    for (int cc = 0; cc < 4; ++cc) {
      int c = (w << 2) + cc;
      int row = (c << 3) + (lane >> 3);
      int gslot = (lane & 7) ^ (row & 7);
      gload16(hT + ((long)b*256 + row)*1024 + k0 + gslot*8, hbuf + c*512);
    }
  };

  stage(0, 0);
  __syncthreads();
  int cur = 0;
  for (int kt = 0; kt < 16; ++kt) {
    if (kt < 15) stage(cur ^ 1, kt + 1);
    const char* gcur = (const char*)(smem + cur*8192);
    const char* hcur = (const char*)(smem + 16384 + cur*32768);
    // ---- QK^T (swapped: A=g rows=keys, B=f cols=q) + exp + packed P write ----
    #pragma unroll
    for (int kc2 = 0; kc2 < 2; ++kc2) {
      f32x16 s2 = {};
      #pragma unroll
      for (int ks = 0; ks < 4; ++ks) {
        int key = kc2*32 + l31;
        bf16x8 gb = *(const bf16x8*)(gcur + key*128 + (((ks*2 + hi) ^ (l31 & 7)) << 4));
        s2 = mfma32(gb, fq[ks], s2);
      }
      #pragma unroll
      for (int g2 = 0; g2 < 4; ++g2) {
        float p0 = __expf(s2[g2*4+0]), p1 = __expf(s2[g2*4+1]);
        float p2 = __expf(s2[g2*4+2]), p3 = __expf(s2[g2*4+3]);
        rsq += (p0 + p1) + (p2 + p3);
        uint2 pk; pk.x = pack2(p0, p1); pk.y = pack2(p2, p3);
        int byteoff = l31*128 + ((((kc2*4 + g2) ^ (l31 & 7)) << 4) + hi*8);
        *(uint2*)((char*)Pw + byteoff) = pk;
      }
    }
    asm volatile("s_waitcnt lgkmcnt(0)" ::: "memory");
    __builtin_amdgcn_sched_barrier(0);
    // ---- PV (swapped: A=hT rows=n, B=P cols=q) ----
    __builtin_amdgcn_s_setprio(1);
    #pragma unroll
    for (int ks = 0; ks < 4; ++ks) {
      bf16x8 pa = *(const bf16x8*)((const char*)Pw + l31*128 + (((ks*2 + hi) ^ (l31 & 7)) << 4));
      #pragma unroll
      for (int nc2 = 0; nc2 < 8; ++nc2) {
        int n = nc2*32 + l31;
        bf16x8 hb = *(const bf16x8*)(hcur + n*128 + (((ks*2 + hi) ^ (l31 & 7)) << 4));
        acc2[nc2] = mfma32(hb, pa, acc2[nc2]);
      }
    }
    __builtin_amdgcn_s_setprio(0);
    __syncthreads();   // drains vmcnt (next tile landed) + protects buffers
    cur ^= 1;
  }
  // ---- normalize + packed y write: q = l31 is lane-local ----
  rsq += __shfl_xor(rsq, 32);
  float ri = 1.f / rsq;
  short* yrow = y + ((long)b*4096 + q0 + w*32 + l31) * 256;
  #pragma unroll
  for (int nc2 = 0; nc2 < 8; ++nc2)
    #pragma unroll
    for (int g2 = 0; g2 < 4; ++g2) {
      short4 o;
      o.x = f2bf(acc2[nc2][g2*4+0] * ri);
      o.y = f2bf(acc2[nc2][g2*4+1] * ri);
      o.z = f2bf(acc2[nc2][g2*4+2] * ri);
      o.w = f2bf(acc2[nc2][g2*4+3] * ri);
      *(short4*)(yrow + nc2*32 + g2*8 + hi*4) = o;
    }
}

// ---------------- out = y[65536,256] @ WoT[512,256]^T + x (f32 out) --------------------
__global__ __launch_bounds__(256) void gemm_out(const short* __restrict__ y,
    const short* __restrict__ WoT, const float* __restrict__ x, float* __restrict__ out) {
  __shared__ short As[128*64];
  __shared__ short Bs[128*64];
  const int m0 = blockIdx.x * 128, n0 = blockIdx.y * 128;
  const int tid = threadIdx.x, w = tid >> 6, lane = tid & 63;
  const int l15 = lane & 15, lhi = lane >> 4;
  const int wr = w >> 1, wc = w & 1;
  f32x4 acc[4][4] = {};
  for (int kt = 0; kt < 4; ++kt) {
    const int k0 = kt * 64;
    stage64<false>(As, y   + (long)m0*256 + k0, 128, 256, tid);
    stage64<false>(Bs, WoT + (long)n0*256 + k0, 128, 256, tid);
    __syncthreads();
    bf16x8 af[4][2], bfr[4][2];
    #pragma unroll
    for (int mi = 0; mi < 4; ++mi)
      #pragma unroll
      for (int ks = 0; ks < 2; ++ks) {
        int m = wr*64 + mi*16 + l15;
        int slot = lhi + ks*4;
        af[mi][ks] = *(const bf16x8*)((const char*)As + m*128 + ((slot ^ (m & 7)) << 4));
      }
    #pragma unroll
    for (int ni = 0; ni < 4; ++ni)
      #pragma unroll
      for (int ks = 0; ks < 2; ++ks) {
        int n = wc*64 + ni*16 + l15;
        int slot = lhi + ks*4;
        bfr[ni][ks] = *(const bf16x8*)((const char*)Bs + n*128 + ((slot ^ (n & 7)) << 4));
      }
    #pragma unroll
    for (int ks = 0; ks < 2; ++ks)
      #pragma unroll
      for (int mi = 0; mi < 4; ++mi)
        #pragma unroll
        for (int ni = 0; ni < 4; ++ni)
          acc[mi][ni] = mfma16(af[mi][ks], bfr[ni][ks], acc[mi][ni]);
    __syncthreads();
  }
  #pragma unroll
  for (int mi = 0; mi < 4; ++mi)
    #pragma unroll
    for (int ni = 0; ni < 4; ++ni)
      #pragma unroll
      for (int r = 0; r < 4; ++r) {
        long row = m0 + wr*64 + mi*16 + lhi*4 + r;
        long col = n0 + wc*64 + ni*16 + l15;
        long idx = row*512 + col;
        out[idx] = acc[mi][ni][r] + x[idx];
      }
}

extern "C" void kernel_launch(void* const* d_in, const int* in_sizes, int n_in,
                              void* d_out, int out_size, void* d_ws, size_t ws_size,
                              hipStream_t stream) {
  const float* x  = (const float*)d_in[0];
  const float* Wf = (const float*)d_in[1];
  const float* Wg = (const float*)d_in[2];
  const float* Wh = (const float*)d_in[3];
  const float* Wo = (const float*)d_in[4];
  float* out = (float*)d_out;

  // workspace carve-up (bf16 elements)
  short* xp  = (short*)d_ws;                    // [16*1024, 512]
  short* fb  = xp  + (long)16*1024*512;         // [65536, 64]
  short* gb  = fb  + (long)65536*64;            // [16384, 64]
  short* hb  = gb  + (long)16384*64;            // [16384, 256]
  short* hTb = hb  + (long)16384*256;           // [16*256, 1024]
  short* yb  = hTb + (long)16*256*1024;         // [65536, 256]
  short* WfT = yb  + (long)65536*256;           // [64, 512]
  short* WgT = WfT + 64*512;
  short* WhT = WgT + 64*512;
  short* WoT = WhT + 256*512;

  hipFuncSetAttribute((const void*)attn_kernel,
                      hipFuncAttributeMaxDynamicSharedMemorySize, 114688);

  prep_weights<<<1536, 256, 0, stream>>>(Wf, Wg, Wh, Wo, WfT, WgT, WhT, WoT);
  gemm_k512<true , true ><<<dim3(512, 1), 256, 0, stream>>>((const void*)x,  WfT, fb, 64,  xp);
  gemm_k512<false, false><<<dim3(128, 1), 256, 0, stream>>>((const void*)xp, WgT, gb, 64,  nullptr);
  gemm_k512<false, false><<<dim3(128, 4), 256, 0, stream>>>((const void*)xp, WhT, hb, 256, nullptr);
  transpose_h <<<dim3(16, 4, 16), 256, 0, stream>>>(hb, hTb);
  attn_kernel <<<dim3(16, 16), 512, 114688, stream>>>(fb, gb, hTb, yb);
  gemm_out    <<<dim3(512, 4), 256, 0, stream>>>(yb, WoT, x, out);
}

// Round 3
// 207.792 us; speedup vs baseline: 1.3370x; 1.0177x over previous
//
#include <hip/hip_runtime.h>

// Attention_86423331930517 — MI355X bf16-MFMA implementation, round 3.
// B=16, H=W=64, C=512, HW=4096, P=1024 pooled pixels, D=64 (qk dim), DV=256 (v dim).
// Round-3 change: out-projection (y@Wo + x) fused into attn epilogue via
// cvt_pk + v_permlane32_swap_b32 in-register y^T fragment assembly (T12).

#define DEVI static __device__ __forceinline__

typedef float f32x4  __attribute__((ext_vector_type(4)));
typedef float f32x16 __attribute__((ext_vector_type(16)));
typedef short bf16x8 __attribute__((ext_vector_type(8)));

DEVI short f2bf(float f) {
  union { float f; unsigned u; } v; v.f = f;
  unsigned r = v.u + 0x7FFFu + ((v.u >> 16) & 1u);   // RNE
  return (short)(r >> 16);
}
DEVI float b2f(short s) {
  union { unsigned u; float f; } v; v.u = ((unsigned)(unsigned short)s) << 16; return v.f;
}
DEVI unsigned pack2(float a, float b) {
  return (unsigned)(unsigned short)f2bf(a) | ((unsigned)(unsigned short)f2bf(b) << 16);
}
DEVI f32x4 mfma16(bf16x8 a, bf16x8 b, f32x4 c) {
  return __builtin_amdgcn_mfma_f32_16x16x32_bf16(a, b, c, 0, 0, 0);
}
DEVI f32x16 mfma32(bf16x8 a, bf16x8 b, f32x16 c) {
  return __builtin_amdgcn_mfma_f32_32x32x16_bf16(a, b, c, 0, 0, 0);
}
DEVI void gload16(const short* gsrc, short* lds) {
  __builtin_amdgcn_global_load_lds(
      (const __attribute__((address_space(1))) void*)gsrc,
      (__attribute__((address_space(3))) void*)lds, 16, 0, 0);
}

// ---------------- weights: cast to bf16 and transpose so B-operand rows are k-contiguous
__global__ __launch_bounds__(256) void prep_weights(
    const float* __restrict__ Wf, const float* __restrict__ Wg,
    const float* __restrict__ Wh, const float* __restrict__ Wo,
    short* __restrict__ WfT, short* __restrict__ WgT,
    short* __restrict__ WhT, short* __restrict__ WoT) {
  int i = blockIdx.x * 256 + threadIdx.x;   // 0..393215 exactly
  const float* src; short* dst; int K, N, e;
  if (i < 32768)       { src = Wf; dst = WfT; K = 512; N = 64;  e = i; }
  else if (i < 65536)  { src = Wg; dst = WgT; K = 512; N = 64;  e = i - 32768; }
  else if (i < 196608) { src = Wh; dst = WhT; K = 512; N = 256; e = i - 65536; }
  else                 { src = Wo; dst = WoT; K = 256; N = 512; e = i - 196608; }
  int n = e / K, k = e - n * K;            // dst[n][k] = src[k][n]
  dst[e] = f2bf(src[(long)k * N + n]);
}

// ---------------- staging helper: tile of `rows` x 64 bf16 into XOR-swizzled LDS -------
template<bool SRC_F32>
DEVI void stage64(short* lds, const void* gsrc, int rows, int stride, int tid) {
  const int chunks = rows * 8;
  for (int c = tid; c < chunks; c += 256) {
    int row = c >> 3, slot = c & 7;
    int dstb = row*128 + ((slot ^ (row & 7)) << 4);
    bf16x8 v;
    if (SRC_F32) {
      const float* s = (const float*)gsrc + (long)row*stride + slot*8;
      float4 u0 = *(const float4*)s;
      float4 u1 = *(const float4*)(s + 4);
      v[0]=f2bf(u0.x); v[1]=f2bf(u0.y); v[2]=f2bf(u0.z); v[3]=f2bf(u0.w);
      v[4]=f2bf(u1.x); v[5]=f2bf(u1.y); v[6]=f2bf(u1.z); v[7]=f2bf(u1.w);
    } else {
      v = *(const bf16x8*)((const short*)gsrc + (long)row*stride + slot*8);
    }
    *(bf16x8*)((char*)lds + dstb) = v;
  }
}

// ---------------- generic K=512 GEMM: C[M,Nfull] = A[M,512] @ BT[N,512]^T (bf16 out) ---
template<bool A_F32, bool POOL>
__global__ __launch_bounds__(256) void gemm_k512(const void* __restrict__ A,
    const short* __restrict__ BT, short* __restrict__ C, int Nfull,
    short* __restrict__ xp) {
  __shared__ short As[128*64];
  __shared__ short Bs[64*64];
  const int m0 = blockIdx.x * 128;
  const int n0 = blockIdx.y * 64;
  const int tid = threadIdx.x, w = tid >> 6, lane = tid & 63;
  const int l15 = lane & 15, lhi = lane >> 4;
  const int wr = w >> 1, wc = w & 1;
  f32x4 acc[4][2] = {};
  for (int kt = 0; kt < 8; ++kt) {
    const int k0 = kt * 64;
    if constexpr (A_F32)
      stage64<true >(As, (const float*)A + (long)m0*512 + k0, 128, 512, tid);
    else
      stage64<false>(As, (const short*)A + (long)m0*512 + k0, 128, 512, tid);
    stage64<false>(Bs, BT + (long)n0*512 + k0, 64, 512, tid);
    __syncthreads();
    if constexpr (POOL) {
      const long pr0 = (long)(m0 >> 12)*1024 + ((m0 & 4095) >> 7)*32;
      int wp = tid >> 3, cs = tid & 7;
      const char* Ab = (const char*)As;
      bf16x8 v00 = *(const bf16x8*)(Ab + (2*wp  )*128 + ((cs ^ ((2*wp  )&7))<<4));
      bf16x8 v01 = *(const bf16x8*)(Ab + (2*wp+1)*128 + ((cs ^ ((2*wp+1)&7))<<4));
      bf16x8 v10 = *(const bf16x8*)(Ab + (64+2*wp)*128 + ((cs ^ ((2*wp  )&7))<<4));
      bf16x8 v11 = *(const bf16x8*)(Ab + (65+2*wp)*128 + ((cs ^ ((2*wp+1)&7))<<4));
      bf16x8 o;
      #pragma unroll
      for (int j = 0; j < 8; ++j)
        o[j] = f2bf(0.25f*(b2f(v00[j])+b2f(v01[j])+b2f(v10[j])+b2f(v11[j])));
      *(bf16x8*)(xp + (pr0 + wp)*512 + k0 + cs*8) = o;
    }
    bf16x8 af[4][2], bfr[2][2];
    #pragma unroll
    for (int mi = 0; mi < 4; ++mi)
      #pragma unroll
      for (int ks = 0; ks < 2; ++ks) {
        int m = wr*64 + mi*16 + l15;
        int slot = lhi + ks*4;
        af[mi][ks] = *(const bf16x8*)((const char*)As + m*128 + ((slot ^ (m & 7)) << 4));
      }
    #pragma unroll
    for (int ni = 0; ni < 2; ++ni)
      #pragma unroll
      for (int ks = 0; ks < 2; ++ks) {
        int n = wc*32 + ni*16 + l15;
        int slot = lhi + ks*4;
        bfr[ni][ks] = *(const bf16x8*)((const char*)Bs + n*128 + ((slot ^ (n & 7)) << 4));
      }
    #pragma unroll
    for (int ks = 0; ks < 2; ++ks)
      #pragma unroll
      for (int mi = 0; mi < 4; ++mi)
        #pragma unroll
        for (int ni = 0; ni < 2; ++ni)
          acc[mi][ni] = mfma16(af[mi][ks], bfr[ni][ks], acc[mi][ni]);
    __syncthreads();
  }
  #pragma unroll
  for (int mi = 0; mi < 4; ++mi)
    #pragma unroll
    for (int ni = 0; ni < 2; ++ni)
      #pragma unroll
      for (int r = 0; r < 4; ++r) {
        long row = m0 + wr*64 + mi*16 + lhi*4 + r;
        int col = n0 + wc*32 + ni*16 + l15;
        C[row * (long)Nfull + col] = f2bf(acc[mi][ni][r]);
      }
}

// ---------------- h[16*1024,256] -> hT[16*256,1024] (bf16 transpose) -------------------
__global__ __launch_bounds__(256) void transpose_h(const short* __restrict__ h,
                                                   short* __restrict__ hT) {
  __shared__ short t[64][72];
  const int k0 = blockIdx.x * 64, n0 = blockIdx.y * 64, b = blockIdx.z;
  const int tid = threadIdx.x;
  {
    int row = tid >> 2, cch = (tid & 3) * 16;
    const short* src = h + ((long)b*1024 + k0 + row) * 256 + n0 + cch;
    *(bf16x8*)&t[row][cch]     = *(const bf16x8*)src;
    *(bf16x8*)&t[row][cch + 8] = *(const bf16x8*)(src + 8);
  }
  __syncthreads();
  {
    int n = tid >> 2, kch = (tid & 3) * 16;
    bf16x8 lo, hi;
    #pragma unroll
    for (int j = 0; j < 8; ++j) { lo[j] = t[kch + j][n]; hi[j] = t[kch + 8 + j][n]; }
    short* dst = hT + ((long)b*256 + n0 + n) * 1024 + k0 + kch;
    *(bf16x8*)dst       = lo;
    *(bf16x8*)(dst + 8) = hi;
  }
}

// ---------------- fused attention + out-projection, 32x32x16 MFMA, QBLK=256, 8 waves ---
// Swapped QK^T: S = mfma(g, f) -> q=lane&31 lane-local. Swapped PV: y = mfma(hT, P).
// Epilogue: y^T B-frags assembled in-register (pack2 + v_permlane32_swap_b32), then
// out[q][c] = mfma(WoT, y^T) + x[q][c], f32 float4 stores. No barrier in epilogue.
__global__ __launch_bounds__(512, 2) void attn_kernel(const short* __restrict__ f,
    const short* __restrict__ g, const short* __restrict__ hT,
    const short* __restrict__ WoT, const float* __restrict__ x,
    float* __restrict__ out) {
  extern __shared__ __align__(16) char smem[];
  const int b = blockIdx.y, q0 = blockIdx.x * 256;
  const int tid = threadIdx.x, w = tid >> 6, lane = tid & 63;
  const int l31 = lane & 31, hi = lane >> 5;

  short* Pw = (short*)(smem + 81920 + w*4096);   // per-wave P strip [32 q][64 keys]

  bf16x8 fq[4];
  {
    const short* frow = f + ((long)b*4096 + q0 + w*32 + l31) * 64;
    #pragma unroll
    for (int ks = 0; ks < 4; ++ks) fq[ks] = *(const bf16x8*)(frow + ks*16 + hi*8);
  }

  f32x16 acc2[8] = {};     // [nc2] : n = nc2*32 + (g&3)+8*(g>>2)+4*hi, q = l31
  float rsq = 0.f;

  auto stage = [&](int buf, int kt) {
    const int k0 = kt * 64;
    short* gbuf = (short*)(smem + buf*8192);
    short* hbuf = (short*)(smem + 16384 + buf*32768);
    {
      int row = (w << 3) + (lane >> 3);
      int gslot = (lane & 7) ^ (row & 7);
      gload16(g + ((long)b*1024 + k0 + row)*64 + gslot*8, gbuf + w*512);
    }
    #pragma unroll
    for (int cc = 0; cc < 4; ++cc) {
      int c = (w << 2) + cc;
      int row = (c << 3) + (lane >> 3);
      int gslot = (lane & 7) ^ (row & 7);
      gload16(hT + ((long)b*256 + row)*1024 + k0 + gslot*8, hbuf + c*512);
    }
  };

  stage(0, 0);
  __syncthreads();
  int cur = 0;
  for (int kt = 0; kt < 16; ++kt) {
    if (kt < 15) stage(cur ^ 1, kt + 1);
    const char* gcur = (const char*)(smem + cur*8192);
    const char* hcur = (const char*)(smem + 16384 + cur*32768);
    // ---- QK^T (swapped) + exp + packed P write ----
    #pragma unroll
    for (int kc2 = 0; kc2 < 2; ++kc2) {
      f32x16 s2 = {};
      #pragma unroll
      for (int ks = 0; ks < 4; ++ks) {
        int key = kc2*32 + l31;
        bf16x8 gb = *(const bf16x8*)(gcur + key*128 + (((ks*2 + hi) ^ (l31 & 7)) << 4));
        s2 = mfma32(gb, fq[ks], s2);
      }
      #pragma unroll
      for (int g2 = 0; g2 < 4; ++g2) {
        float p0 = __expf(s2[g2*4+0]), p1 = __expf(s2[g2*4+1]);
        float p2 = __expf(s2[g2*4+2]), p3 = __expf(s2[g2*4+3]);
        rsq += (p0 + p1) + (p2 + p3);
        uint2 pk; pk.x = pack2(p0, p1); pk.y = pack2(p2, p3);
        int byteoff = l31*128 + ((((kc2*4 + g2) ^ (l31 & 7)) << 4) + hi*8);
        *(uint2*)((char*)Pw + byteoff) = pk;
      }
    }
    asm volatile("s_waitcnt lgkmcnt(0)" ::: "memory");
    __builtin_amdgcn_sched_barrier(0);
    // ---- PV (swapped) ----
    __builtin_amdgcn_s_setprio(1);
    #pragma unroll
    for (int ks = 0; ks < 4; ++ks) {
      bf16x8 pa = *(const bf16x8*)((const char*)Pw + l31*128 + (((ks*2 + hi) ^ (l31 & 7)) << 4));
      #pragma unroll
      for (int nc2 = 0; nc2 < 8; ++nc2) {
        int n = nc2*32 + l31;
        bf16x8 hb = *(const bf16x8*)(hcur + n*128 + (((ks*2 + hi) ^ (l31 & 7)) << 4));
        acc2[nc2] = mfma32(hb, pa, acc2[nc2]);
      }
    }
    __builtin_amdgcn_s_setprio(0);
    __syncthreads();
    cur ^= 1;
  }
  // ---- normalize + assemble y^T B-frags in-register (T12) ----
  rsq += __shfl_xor(rsq, 32);
  float ri = 1.f / rsq;
  bf16x8 yB[16];
  #pragma unroll
  for (int nc2 = 0; nc2 < 8; ++nc2) {
    #pragma unroll
    for (int fh = 0; fh < 2; ++fh) {
      const int G = fh*8;
      unsigned a0 = pack2(acc2[nc2][G+0]*ri, acc2[nc2][G+1]*ri);
      unsigned a1 = pack2(acc2[nc2][G+2]*ri, acc2[nc2][G+3]*ri);
      unsigned b0 = pack2(acc2[nc2][G+4]*ri, acc2[nc2][G+5]*ri);
      unsigned b1 = pack2(acc2[nc2][G+6]*ri, acc2[nc2][G+7]*ri);
      // swap low(vdst) <-> high(vsrc): after, b0=[a0.hi|b0.hi]=d2, a0=[a0.lo|b0.lo]=d0
      asm volatile("v_permlane32_swap_b32 %0, %1" : "+v"(b0), "+v"(a0));
      asm volatile("v_permlane32_swap_b32 %0, %1" : "+v"(b1), "+v"(a1));
      union { unsigned u[4]; bf16x8 v; } pk;
      pk.u[0] = a0; pk.u[1] = a1; pk.u[2] = b0; pk.u[3] = b1;
      yB[nc2*2 + fh] = pk.v;
    }
  }
  // ---- out-GEMM: out[q][c] = sum_n Wo[n][c]*y[q][n] + x[q][c], register-only ----
  const long qrow = (long)b*4096 + q0 + w*32 + l31;
  const float* xrow = x + qrow*512;
  float* orow = out + qrow*512;
  for (int cc2 = 0; cc2 < 16; ++cc2) {
    f32x16 ao = {};
    #pragma unroll
    for (int ns = 0; ns < 16; ++ns) {
      bf16x8 wo = *(const bf16x8*)(WoT + (cc2*32 + l31)*256 + ns*16 + hi*8);
      ao = mfma32(wo, yB[ns], ao);
    }
    #pragma unroll
    for (int g2 = 0; g2 < 4; ++g2) {
      int c = cc2*32 + g2*8 + hi*4;
      float4 xv = *(const float4*)(xrow + c);
      float4 ov;
      ov.x = ao[g2*4+0] + xv.x;
      ov.y = ao[g2*4+1] + xv.y;
      ov.z = ao[g2*4+2] + xv.z;
      ov.w = ao[g2*4+3] + xv.w;
      *(float4*)(orow + c) = ov;
    }
  }
}

extern "C" void kernel_launch(void* const* d_in, const int* in_sizes, int n_in,
                              void* d_out, int out_size, void* d_ws, size_t ws_size,
                              hipStream_t stream) {
  const float* x  = (const float*)d_in[0];
  const float* Wf = (const float*)d_in[1];
  const float* Wg = (const float*)d_in[2];
  const float* Wh = (const float*)d_in[3];
  const float* Wo = (const float*)d_in[4];
  float* out = (float*)d_out;

  // workspace carve-up (bf16 elements)
  short* xp  = (short*)d_ws;                    // [16*1024, 512]
  short* fb  = xp  + (long)16*1024*512;         // [65536, 64]
  short* gb  = fb  + (long)65536*64;            // [16384, 64]
  short* hb  = gb  + (long)16384*64;            // [16384, 256]
  short* hTb = hb  + (long)16384*256;           // [16*256, 1024]
  short* WfT = hTb + (long)16*256*1024;         // [64, 512]
  short* WgT = WfT + 64*512;
  short* WhT = WgT + 64*512;
  short* WoT = WhT + 256*512;

  hipFuncSetAttribute((const void*)attn_kernel,
                      hipFuncAttributeMaxDynamicSharedMemorySize, 114688);

  prep_weights<<<1536, 256, 0, stream>>>(Wf, Wg, Wh, Wo, WfT, WgT, WhT, WoT);
  gemm_k512<true , true ><<<dim3(512, 1), 256, 0, stream>>>((const void*)x,  WfT, fb, 64,  xp);
  gemm_k512<false, false><<<dim3(128, 1), 256, 0, stream>>>((const void*)xp, WgT, gb, 64,  nullptr);
  gemm_k512<false, false><<<dim3(128, 4), 256, 0, stream>>>((const void*)xp, WhT, hb, 256, nullptr);
  transpose_h <<<dim3(16, 4, 16), 256, 0, stream>>>(hb, hTb);
  attn_kernel <<<dim3(16, 16), 512, 114688, stream>>>(fb, gb, hTb, WoT, x, out);
}

// Round 4
// 203.989 us; speedup vs baseline: 1.3620x; 1.0186x over previous
//
#include <hip/hip_runtime.h>

// Attention_86423331930517 — MI355X bf16-MFMA implementation, round 4.
// B=16, H=W=64, C=512, HW=4096, P=1024 pooled pixels, D=64 (qk dim), DV=256 (v dim).
// Round-4 changes: P kept in registers via pack2+v_permlane32_swap_b32 (no P LDS,
// no QK->PV lgkmcnt serialization); LDS 112->80KB, QBLK 256->128 with 4 waves,
// grid 512 blocks -> 2 blocks/CU for barrier decoupling; epilogue MFMA chain split.

#define DEVI static __device__ __forceinline__

typedef float f32x4  __attribute__((ext_vector_type(4)));
typedef float f32x16 __attribute__((ext_vector_type(16)));
typedef short bf16x8 __attribute__((ext_vector_type(8)));

DEVI short f2bf(float f) {
  union { float f; unsigned u; } v; v.f = f;
  unsigned r = v.u + 0x7FFFu + ((v.u >> 16) & 1u);   // RNE
  return (short)(r >> 16);
}
DEVI float b2f(short s) {
  union { unsigned u; float f; } v; v.u = ((unsigned)(unsigned short)s) << 16; return v.f;
}
DEVI unsigned pack2(float a, float b) {
  return (unsigned)(unsigned short)f2bf(a) | ((unsigned)(unsigned short)f2bf(b) << 16);
}
DEVI f32x4 mfma16(bf16x8 a, bf16x8 b, f32x4 c) {
  return __builtin_amdgcn_mfma_f32_16x16x32_bf16(a, b, c, 0, 0, 0);
}
DEVI f32x16 mfma32(bf16x8 a, bf16x8 b, f32x16 c) {
  return __builtin_amdgcn_mfma_f32_32x32x16_bf16(a, b, c, 0, 0, 0);
}
DEVI void gload16(const short* gsrc, short* lds) {
  __builtin_amdgcn_global_load_lds(
      (const __attribute__((address_space(1))) void*)gsrc,
      (__attribute__((address_space(3))) void*)lds, 16, 0, 0);
}

// ---------------- weights: cast to bf16 and transpose so B-operand rows are k-contiguous
__global__ __launch_bounds__(256) void prep_weights(
    const float* __restrict__ Wf, const float* __restrict__ Wg,
    const float* __restrict__ Wh, const float* __restrict__ Wo,
    short* __restrict__ WfT, short* __restrict__ WgT,
    short* __restrict__ WhT, short* __restrict__ WoT) {
  int i = blockIdx.x * 256 + threadIdx.x;   // 0..393215 exactly
  const float* src; short* dst; int K, N, e;
  if (i < 32768)       { src = Wf; dst = WfT; K = 512; N = 64;  e = i; }
  else if (i < 65536)  { src = Wg; dst = WgT; K = 512; N = 64;  e = i - 32768; }
  else if (i < 196608) { src = Wh; dst = WhT; K = 512; N = 256; e = i - 65536; }
  else                 { src = Wo; dst = WoT; K = 256; N = 512; e = i - 196608; }
  int n = e / K, k = e - n * K;            // dst[n][k] = src[k][n]
  dst[e] = f2bf(src[(long)k * N + n]);
}

// ---------------- staging helper: tile of `rows` x 64 bf16 into XOR-swizzled LDS -------
template<bool SRC_F32>
DEVI void stage64(short* lds, const void* gsrc, int rows, int stride, int tid) {
  const int chunks = rows * 8;
  for (int c = tid; c < chunks; c += 256) {
    int row = c >> 3, slot = c & 7;
    int dstb = row*128 + ((slot ^ (row & 7)) << 4);
    bf16x8 v;
    if (SRC_F32) {
      const float* s = (const float*)gsrc + (long)row*stride + slot*8;
      float4 u0 = *(const float4*)s;
      float4 u1 = *(const float4*)(s + 4);
      v[0]=f2bf(u0.x); v[1]=f2bf(u0.y); v[2]=f2bf(u0.z); v[3]=f2bf(u0.w);
      v[4]=f2bf(u1.x); v[5]=f2bf(u1.y); v[6]=f2bf(u1.z); v[7]=f2bf(u1.w);
    } else {
      v = *(const bf16x8*)((const short*)gsrc + (long)row*stride + slot*8);
    }
    *(bf16x8*)((char*)lds + dstb) = v;
  }
}

// ---------------- generic K=512 GEMM: C[M,Nfull] = A[M,512] @ BT[N,512]^T (bf16 out) ---
template<bool A_F32, bool POOL>
__global__ __launch_bounds__(256) void gemm_k512(const void* __restrict__ A,
    const short* __restrict__ BT, short* __restrict__ C, int Nfull,
    short* __restrict__ xp) {
  __shared__ short As[128*64];
  __shared__ short Bs[64*64];
  const int m0 = blockIdx.x * 128;
  const int n0 = blockIdx.y * 64;
  const int tid = threadIdx.x, w = tid >> 6, lane = tid & 63;
  const int l15 = lane & 15, lhi = lane >> 4;
  const int wr = w >> 1, wc = w & 1;
  f32x4 acc[4][2] = {};
  for (int kt = 0; kt < 8; ++kt) {
    const int k0 = kt * 64;
    if constexpr (A_F32)
      stage64<true >(As, (const float*)A + (long)m0*512 + k0, 128, 512, tid);
    else
      stage64<false>(As, (const short*)A + (long)m0*512 + k0, 128, 512, tid);
    stage64<false>(Bs, BT + (long)n0*512 + k0, 64, 512, tid);
    __syncthreads();
    if constexpr (POOL) {
      const long pr0 = (long)(m0 >> 12)*1024 + ((m0 & 4095) >> 7)*32;
      int wp = tid >> 3, cs = tid & 7;
      const char* Ab = (const char*)As;
      bf16x8 v00 = *(const bf16x8*)(Ab + (2*wp  )*128 + ((cs ^ ((2*wp  )&7))<<4));
      bf16x8 v01 = *(const bf16x8*)(Ab + (2*wp+1)*128 + ((cs ^ ((2*wp+1)&7))<<4));
      bf16x8 v10 = *(const bf16x8*)(Ab + (64+2*wp)*128 + ((cs ^ ((2*wp  )&7))<<4));
      bf16x8 v11 = *(const bf16x8*)(Ab + (65+2*wp)*128 + ((cs ^ ((2*wp+1)&7))<<4));
      bf16x8 o;
      #pragma unroll
      for (int j = 0; j < 8; ++j)
        o[j] = f2bf(0.25f*(b2f(v00[j])+b2f(v01[j])+b2f(v10[j])+b2f(v11[j])));
      *(bf16x8*)(xp + (pr0 + wp)*512 + k0 + cs*8) = o;
    }
    bf16x8 af[4][2], bfr[2][2];
    #pragma unroll
    for (int mi = 0; mi < 4; ++mi)
      #pragma unroll
      for (int ks = 0; ks < 2; ++ks) {
        int m = wr*64 + mi*16 + l15;
        int slot = lhi + ks*4;
        af[mi][ks] = *(const bf16x8*)((const char*)As + m*128 + ((slot ^ (m & 7)) << 4));
      }
    #pragma unroll
    for (int ni = 0; ni < 2; ++ni)
      #pragma unroll
      for (int ks = 0; ks < 2; ++ks) {
        int n = wc*32 + ni*16 + l15;
        int slot = lhi + ks*4;
        bfr[ni][ks] = *(const bf16x8*)((const char*)Bs + n*128 + ((slot ^ (n & 7)) << 4));
      }
    #pragma unroll
    for (int ks = 0; ks < 2; ++ks)
      #pragma unroll
      for (int mi = 0; mi < 4; ++mi)
        #pragma unroll
        for (int ni = 0; ni < 2; ++ni)
          acc[mi][ni] = mfma16(af[mi][ks], bfr[ni][ks], acc[mi][ni]);
    __syncthreads();
  }
  #pragma unroll
  for (int mi = 0; mi < 4; ++mi)
    #pragma unroll
    for (int ni = 0; ni < 2; ++ni)
      #pragma unroll
      for (int r = 0; r < 4; ++r) {
        long row = m0 + wr*64 + mi*16 + lhi*4 + r;
        int col = n0 + wc*32 + ni*16 + l15;
        C[row * (long)Nfull + col] = f2bf(acc[mi][ni][r]);
      }
}

// ---------------- h[16*1024,256] -> hT[16*256,1024] (bf16 transpose) -------------------
__global__ __launch_bounds__(256) void transpose_h(const short* __restrict__ h,
                                                   short* __restrict__ hT) {
  __shared__ short t[64][72];
  const int k0 = blockIdx.x * 64, n0 = blockIdx.y * 64, b = blockIdx.z;
  const int tid = threadIdx.x;
  {
    int row = tid >> 2, cch = (tid & 3) * 16;
    const short* src = h + ((long)b*1024 + k0 + row) * 256 + n0 + cch;
    *(bf16x8*)&t[row][cch]     = *(const bf16x8*)src;
    *(bf16x8*)&t[row][cch + 8] = *(const bf16x8*)(src + 8);
  }
  __syncthreads();
  {
    int n = tid >> 2, kch = (tid & 3) * 16;
    bf16x8 lo, hi;
    #pragma unroll
    for (int j = 0; j < 8; ++j) { lo[j] = t[kch + j][n]; hi[j] = t[kch + 8 + j][n]; }
    short* dst = hT + ((long)b*256 + n0 + n) * 1024 + k0 + kch;
    *(bf16x8*)dst       = lo;
    *(bf16x8*)(dst + 8) = hi;
  }
}

// ---------------- fused attention + out-projection, 32x32x16 MFMA, QBLK=128, 4 waves ---
// Swapped QK^T: S = mfma(g, f) -> q=lane&31 lane-local. P assembled IN-REGISTER via
// pack2 + v_permlane32_swap_b32 (same redistribution as epilogue y^T). Swapped PV:
// y = mfma(hT, P). Epilogue: out[q][c] = mfma(WoT, y^T) + x, split accumulator chain.
// LDS 80KB (g dbuf 16K + hT dbuf 64K) -> 2 blocks/CU.
__global__ __launch_bounds__(256, 2) void attn_kernel(const short* __restrict__ f,
    const short* __restrict__ g, const short* __restrict__ hT,
    const short* __restrict__ WoT, const float* __restrict__ x,
    float* __restrict__ out) {
  extern __shared__ __align__(16) char smem[];
  const int b = blockIdx.y, q0 = blockIdx.x * 128;
  const int tid = threadIdx.x, w = tid >> 6, lane = tid & 63;
  const int l31 = lane & 31, hi = lane >> 5;

  bf16x8 fq[4];
  {
    const short* frow = f + ((long)b*4096 + q0 + w*32 + l31) * 64;
    #pragma unroll
    for (int ks = 0; ks < 4; ++ks) fq[ks] = *(const bf16x8*)(frow + ks*16 + hi*8);
  }

  f32x16 acc2[8] = {};     // [nc2] : n = nc2*32 + (g&3)+8*(g>>2)+4*hi, q = l31
  float rsq = 0.f;

  auto stage = [&](int buf, int kt) {
    const int k0 = kt * 64;
    short* gbuf = (short*)(smem + buf*8192);
    short* hbuf = (short*)(smem + 16384 + buf*32768);
    #pragma unroll
    for (int it = 0; it < 2; ++it) {          // g: 64 rows x 8 slots = 512 chunks
      int c = it*256 + w*64 + lane;
      int row = c >> 3, gslot = (c & 7) ^ (row & 7);
      gload16(g + ((long)b*1024 + k0 + row)*64 + gslot*8, gbuf + (it*256 + w*64)*8);
    }
    #pragma unroll
    for (int it = 0; it < 8; ++it) {          // hT: 256 rows x 8 slots = 2048 chunks
      int c = it*256 + w*64 + lane;
      int row = c >> 3, gslot = (c & 7) ^ (row & 7);
      gload16(hT + ((long)b*256 + row)*1024 + k0 + gslot*8, hbuf + (it*256 + w*64)*8);
    }
  };

  stage(0, 0);
  __syncthreads();
  int cur = 0;
  for (int kt = 0; kt < 16; ++kt) {
    if (kt < 15) stage(cur ^ 1, kt + 1);
    const char* gcur = (const char*)(smem + cur*8192);
    const char* hcur = (const char*)(smem + 16384 + cur*32768);
    // ---- QK^T (swapped) + exp + in-register P^T fragment assembly ----
    bf16x8 pa[4];
    #pragma unroll
    for (int kc2 = 0; kc2 < 2; ++kc2) {
      f32x16 s2 = {};
      #pragma unroll
      for (int ks = 0; ks < 4; ++ks) {
        int key = kc2*32 + l31;
        bf16x8 gb = *(const bf16x8*)(gcur + key*128 + (((ks*2 + hi) ^ (l31 & 7)) << 4));
        s2 = mfma32(gb, fq[ks], s2);
      }
      #pragma unroll
      for (int fh = 0; fh < 2; ++fh) {
        const int G = fh*8;
        float e0 = __expf(s2[G+0]), e1 = __expf(s2[G+1]);
        float e2 = __expf(s2[G+2]), e3 = __expf(s2[G+3]);
        float e4 = __expf(s2[G+4]), e5 = __expf(s2[G+5]);
        float e6 = __expf(s2[G+6]), e7 = __expf(s2[G+7]);
        rsq += ((e0 + e1) + (e2 + e3)) + ((e4 + e5) + (e6 + e7));
        unsigned a0 = pack2(e0, e1), a1 = pack2(e2, e3);
        unsigned b0 = pack2(e4, e5), b1 = pack2(e6, e7);
        asm volatile("v_permlane32_swap_b32 %0, %1" : "+v"(b0), "+v"(a0));
        asm volatile("v_permlane32_swap_b32 %0, %1" : "+v"(b1), "+v"(a1));
        union { unsigned u[4]; bf16x8 v; } pk;
        pk.u[0] = a0; pk.u[1] = a1; pk.u[2] = b0; pk.u[3] = b1;
        pa[kc2*2 + fh] = pk.v;
      }
    }
    // ---- PV (swapped), P from registers ----
    __builtin_amdgcn_s_setprio(1);
    #pragma unroll
    for (int ks = 0; ks < 4; ++ks) {
      #pragma unroll
      for (int nc2 = 0; nc2 < 8; ++nc2) {
        int n = nc2*32 + l31;
        bf16x8 hb = *(const bf16x8*)(hcur + n*128 + (((ks*2 + hi) ^ (l31 & 7)) << 4));
        acc2[nc2] = mfma32(hb, pa[ks], acc2[nc2]);
      }
    }
    __builtin_amdgcn_s_setprio(0);
    __syncthreads();
    cur ^= 1;
  }
  // ---- normalize + assemble y^T B-frags in-register ----
  rsq += __shfl_xor(rsq, 32);
  float ri = 1.f / rsq;
  bf16x8 yB[16];
  #pragma unroll
  for (int nc2 = 0; nc2 < 8; ++nc2) {
    #pragma unroll
    for (int fh = 0; fh < 2; ++fh) {
      const int G = fh*8;
      unsigned a0 = pack2(acc2[nc2][G+0]*ri, acc2[nc2][G+1]*ri);
      unsigned a1 = pack2(acc2[nc2][G+2]*ri, acc2[nc2][G+3]*ri);
      unsigned b0 = pack2(acc2[nc2][G+4]*ri, acc2[nc2][G+5]*ri);
      unsigned b1 = pack2(acc2[nc2][G+6]*ri, acc2[nc2][G+7]*ri);
      asm volatile("v_permlane32_swap_b32 %0, %1" : "+v"(b0), "+v"(a0));
      asm volatile("v_permlane32_swap_b32 %0, %1" : "+v"(b1), "+v"(a1));
      union { unsigned u[4]; bf16x8 v; } pk;
      pk.u[0] = a0; pk.u[1] = a1; pk.u[2] = b0; pk.u[3] = b1;
      yB[nc2*2 + fh] = pk.v;
    }
  }
  // ---- out-GEMM: out[q][c] = sum_n Wo[n][c]*y[q][n] + x[q][c], register-only ----
  const long qrow = (long)b*4096 + q0 + w*32 + l31;
  const float* xrow = x + qrow*512;
  float* orow = out + qrow*512;
  for (int cc2 = 0; cc2 < 16; ++cc2) {
    f32x16 ao0 = {}, ao1 = {};
    #pragma unroll
    for (int ns2 = 0; ns2 < 8; ++ns2) {
      bf16x8 wo0 = *(const bf16x8*)(WoT + (cc2*32 + l31)*256 + (2*ns2  )*16 + hi*8);
      bf16x8 wo1 = *(const bf16x8*)(WoT + (cc2*32 + l31)*256 + (2*ns2+1)*16 + hi*8);
      ao0 = mfma32(wo0, yB[2*ns2  ], ao0);
      ao1 = mfma32(wo1, yB[2*ns2+1], ao1);
    }
    #pragma unroll
    for (int g2 = 0; g2 < 4; ++g2) {
      int c = cc2*32 + g2*8 + hi*4;
      float4 xv = *(const float4*)(xrow + c);
      float4 ov;
      ov.x = ao0[g2*4+0] + ao1[g2*4+0] + xv.x;
      ov.y = ao0[g2*4+1] + ao1[g2*4+1] + xv.y;
      ov.z = ao0[g2*4+2] + ao1[g2*4+2] + xv.z;
      ov.w = ao0[g2*4+3] + ao1[g2*4+3] + xv.w;
      *(float4*)(orow + c) = ov;
    }
  }
}

extern "C" void kernel_launch(void* const* d_in, const int* in_sizes, int n_in,
                              void* d_out, int out_size, void* d_ws, size_t ws_size,
                              hipStream_t stream) {
  const float* x  = (const float*)d_in[0];
  const float* Wf = (const float*)d_in[1];
  const float* Wg = (const float*)d_in[2];
  const float* Wh = (const float*)d_in[3];
  const float* Wo = (const float*)d_in[4];
  float* out = (float*)d_out;

  // workspace carve-up (bf16 elements)
  short* xp  = (short*)d_ws;                    // [16*1024, 512]
  short* fb  = xp  + (long)16*1024*512;         // [65536, 64]
  short* gb  = fb  + (long)65536*64;            // [16384, 64]
  short* hb  = gb  + (long)16384*64;            // [16384, 256]
  short* hTb = hb  + (long)16384*256;           // [16*256, 1024]
  short* WfT = hTb + (long)16*256*1024;         // [64, 512]
  short* WgT = WfT + 64*512;
  short* WhT = WgT + 64*512;
  short* WoT = WhT + 256*512;

  hipFuncSetAttribute((const void*)attn_kernel,
                      hipFuncAttributeMaxDynamicSharedMemorySize, 81920);

  prep_weights<<<1536, 256, 0, stream>>>(Wf, Wg, Wh, Wo, WfT, WgT, WhT, WoT);
  gemm_k512<true , true ><<<dim3(512, 1), 256, 0, stream>>>((const void*)x,  WfT, fb, 64,  xp);
  gemm_k512<false, false><<<dim3(128, 1), 256, 0, stream>>>((const void*)xp, WgT, gb, 64,  nullptr);
  gemm_k512<false, false><<<dim3(128, 4), 256, 0, stream>>>((const void*)xp, WhT, hb, 256, nullptr);
  transpose_h <<<dim3(16, 4, 16), 256, 0, stream>>>(hb, hTb);
  attn_kernel <<<dim3(32, 16), 256, 81920, stream>>>(fb, gb, hTb, WoT, x, out);
}

// Round 5
// 203.222 us; speedup vs baseline: 1.3671x; 1.0038x over previous
//
#include <hip/hip_runtime.h>

// Attention_86423331930517 — MI355X bf16-MFMA implementation, round 5.
// B=16, H=W=64, C=512, HW=4096, P=1024 pooled pixels, D=64 (qk dim), DV=256 (v dim).
// Round-5 changes: attn K-loop uses raw s_barrier + counted s_waitcnt vmcnt(10)
// (T3/T4 — prefetch stays in flight across compute instead of being drained by
// __syncthreads' implicit vmcnt(0)); all hot f32->bf16 packing now uses
// v_cvt_pk_bf16_f32 (1 instr per pair vs ~10 VALU for hand-rolled RNE).

#define DEVI static __device__ __forceinline__

typedef float f32x4  __attribute__((ext_vector_type(4)));
typedef float f32x16 __attribute__((ext_vector_type(16)));
typedef short bf16x8 __attribute__((ext_vector_type(8)));

DEVI short f2bf(float f) {
  union { float f; unsigned u; } v; v.f = f;
  unsigned r = v.u + 0x7FFFu + ((v.u >> 16) & 1u);   // RNE
  return (short)(r >> 16);
}
DEVI float b2f(short s) {
  union { unsigned u; float f; } v; v.u = ((unsigned)(unsigned short)s) << 16; return v.f;
}
DEVI unsigned cvtpk(float lo, float hi) {        // dst = {bf16(lo) | bf16(hi)<<16}, RNE
  unsigned r;
  asm("v_cvt_pk_bf16_f32 %0, %1, %2" : "=v"(r) : "v"(lo), "v"(hi));
  return r;
}
DEVI f32x4 mfma16(bf16x8 a, bf16x8 b, f32x4 c) {
  return __builtin_amdgcn_mfma_f32_16x16x32_bf16(a, b, c, 0, 0, 0);
}
DEVI f32x16 mfma32(bf16x8 a, bf16x8 b, f32x16 c) {
  return __builtin_amdgcn_mfma_f32_32x32x16_bf16(a, b, c, 0, 0, 0);
}
DEVI void gload16(const short* gsrc, short* lds) {
  __builtin_amdgcn_global_load_lds(
      (const __attribute__((address_space(1))) void*)gsrc,
      (__attribute__((address_space(3))) void*)lds, 16, 0, 0);
}

// ---------------- weights: cast to bf16 and transpose so B-operand rows are k-contiguous
__global__ __launch_bounds__(256) void prep_weights(
    const float* __restrict__ Wf, const float* __restrict__ Wg,
    const float* __restrict__ Wh, const float* __restrict__ Wo,
    short* __restrict__ WfT, short* __restrict__ WgT,
    short* __restrict__ WhT, short* __restrict__ WoT) {
  int i = blockIdx.x * 256 + threadIdx.x;   // 0..393215 exactly
  const float* src; short* dst; int K, N, e;
  if (i < 32768)       { src = Wf; dst = WfT; K = 512; N = 64;  e = i; }
  else if (i < 65536)  { src = Wg; dst = WgT; K = 512; N = 64;  e = i - 32768; }
  else if (i < 196608) { src = Wh; dst = WhT; K = 512; N = 256; e = i - 65536; }
  else                 { src = Wo; dst = WoT; K = 256; N = 512; e = i - 196608; }
  int n = e / K, k = e - n * K;            // dst[n][k] = src[k][n]
  dst[e] = f2bf(src[(long)k * N + n]);
}

// ---------------- staging helper: tile of `rows` x 64 bf16 into XOR-swizzled LDS -------
template<bool SRC_F32>
DEVI void stage64(short* lds, const void* gsrc, int rows, int stride, int tid) {
  const int chunks = rows * 8;
  for (int c = tid; c < chunks; c += 256) {
    int row = c >> 3, slot = c & 7;
    int dstb = row*128 + ((slot ^ (row & 7)) << 4);
    if (SRC_F32) {
      const float* s = (const float*)gsrc + (long)row*stride + slot*8;
      float4 u0 = *(const float4*)s;
      float4 u1 = *(const float4*)(s + 4);
      union { unsigned u[4]; bf16x8 v; } pk;
      pk.u[0] = cvtpk(u0.x, u0.y); pk.u[1] = cvtpk(u0.z, u0.w);
      pk.u[2] = cvtpk(u1.x, u1.y); pk.u[3] = cvtpk(u1.z, u1.w);
      *(bf16x8*)((char*)lds + dstb) = pk.v;
    } else {
      *(bf16x8*)((char*)lds + dstb) =
          *(const bf16x8*)((const short*)gsrc + (long)row*stride + slot*8);
    }
  }
}

// ---------------- generic K=512 GEMM: C[M,Nfull] = A[M,512] @ BT[N,512]^T (bf16 out) ---
template<bool A_F32, bool POOL>
__global__ __launch_bounds__(256) void gemm_k512(const void* __restrict__ A,
    const short* __restrict__ BT, short* __restrict__ C, int Nfull,
    short* __restrict__ xp) {
  __shared__ short As[128*64];
  __shared__ short Bs[64*64];
  const int m0 = blockIdx.x * 128;
  const int n0 = blockIdx.y * 64;
  const int tid = threadIdx.x, w = tid >> 6, lane = tid & 63;
  const int l15 = lane & 15, lhi = lane >> 4;
  const int wr = w >> 1, wc = w & 1;
  f32x4 acc[4][2] = {};
  for (int kt = 0; kt < 8; ++kt) {
    const int k0 = kt * 64;
    if constexpr (A_F32)
      stage64<true >(As, (const float*)A + (long)m0*512 + k0, 128, 512, tid);
    else
      stage64<false>(As, (const short*)A + (long)m0*512 + k0, 128, 512, tid);
    stage64<false>(Bs, BT + (long)n0*512 + k0, 64, 512, tid);
    __syncthreads();
    if constexpr (POOL) {
      const long pr0 = (long)(m0 >> 12)*1024 + ((m0 & 4095) >> 7)*32;
      int wp = tid >> 3, cs = tid & 7;
      const char* Ab = (const char*)As;
      bf16x8 v00 = *(const bf16x8*)(Ab + (2*wp  )*128 + ((cs ^ ((2*wp  )&7))<<4));
      bf16x8 v01 = *(const bf16x8*)(Ab + (2*wp+1)*128 + ((cs ^ ((2*wp+1)&7))<<4));
      bf16x8 v10 = *(const bf16x8*)(Ab + (64+2*wp)*128 + ((cs ^ ((2*wp  )&7))<<4));
      bf16x8 v11 = *(const bf16x8*)(Ab + (65+2*wp)*128 + ((cs ^ ((2*wp+1)&7))<<4));
      float s[8];
      #pragma unroll
      for (int j = 0; j < 8; ++j)
        s[j] = 0.25f*(b2f(v00[j])+b2f(v01[j])+b2f(v10[j])+b2f(v11[j]));
      union { unsigned u[4]; bf16x8 v; } pk;
      pk.u[0] = cvtpk(s[0], s[1]); pk.u[1] = cvtpk(s[2], s[3]);
      pk.u[2] = cvtpk(s[4], s[5]); pk.u[3] = cvtpk(s[6], s[7]);
      *(bf16x8*)(xp + (pr0 + wp)*512 + k0 + cs*8) = pk.v;
    }
    bf16x8 af[4][2], bfr[2][2];
    #pragma unroll
    for (int mi = 0; mi < 4; ++mi)
      #pragma unroll
      for (int ks = 0; ks < 2; ++ks) {
        int m = wr*64 + mi*16 + l15;
        int slot = lhi + ks*4;
        af[mi][ks] = *(const bf16x8*)((const char*)As + m*128 + ((slot ^ (m & 7)) << 4));
      }
    #pragma unroll
    for (int ni = 0; ni < 2; ++ni)
      #pragma unroll
      for (int ks = 0; ks < 2; ++ks) {
        int n = wc*32 + ni*16 + l15;
        int slot = lhi + ks*4;
        bfr[ni][ks] = *(const bf16x8*)((const char*)Bs + n*128 + ((slot ^ (n & 7)) << 4));
      }
    #pragma unroll
    for (int ks = 0; ks < 2; ++ks)
      #pragma unroll
      for (int mi = 0; mi < 4; ++mi)
        #pragma unroll
        for (int ni = 0; ni < 2; ++ni)
          acc[mi][ni] = mfma16(af[mi][ks], bfr[ni][ks], acc[mi][ni]);
    __syncthreads();
  }
  #pragma unroll
  for (int mi = 0; mi < 4; ++mi)
    #pragma unroll
    for (int ni = 0; ni < 2; ++ni)
      #pragma unroll
      for (int r = 0; r < 4; ++r) {
        long row = m0 + wr*64 + mi*16 + lhi*4 + r;
        int col = n0 + wc*32 + ni*16 + l15;
        C[row * (long)Nfull + col] = f2bf(acc[mi][ni][r]);
      }
}

// ---------------- h[16*1024,256] -> hT[16*256,1024] (bf16 transpose) -------------------
__global__ __launch_bounds__(256) void transpose_h(const short* __restrict__ h,
                                                   short* __restrict__ hT) {
  __shared__ short t[64][72];
  const int k0 = blockIdx.x * 64, n0 = blockIdx.y * 64, b = blockIdx.z;
  const int tid = threadIdx.x;
  {
    int row = tid >> 2, cch = (tid & 3) * 16;
    const short* src = h + ((long)b*1024 + k0 + row) * 256 + n0 + cch;
    *(bf16x8*)&t[row][cch]     = *(const bf16x8*)src;
    *(bf16x8*)&t[row][cch + 8] = *(const bf16x8*)(src + 8);
  }
  __syncthreads();
  {
    int n = tid >> 2, kch = (tid & 3) * 16;
    bf16x8 lo, hi;
    #pragma unroll
    for (int j = 0; j < 8; ++j) { lo[j] = t[kch + j][n]; hi[j] = t[kch + 8 + j][n]; }
    short* dst = hT + ((long)b*256 + n0 + n) * 1024 + k0 + kch;
    *(bf16x8*)dst       = lo;
    *(bf16x8*)(dst + 8) = hi;
  }
}

// ---------------- fused attention + out-projection, 32x32x16 MFMA, QBLK=128, 4 waves ---
// Swapped QK^T: S = mfma(g, f) -> q=lane&31 lane-local. P assembled IN-REGISTER via
// v_cvt_pk_bf16_f32 + v_permlane32_swap_b32. Swapped PV: y = mfma(hT, P).
// K-loop sync: raw s_barrier pairs + counted s_waitcnt vmcnt(10) — prefetched
// global_load_lds stay in flight across the compute phase (never vmcnt(0) mid-loop).
// Epilogue: out[q][c] = mfma(WoT, y^T) + x, register-only, no barriers.
__global__ __launch_bounds__(256, 2) void attn_kernel(const short* __restrict__ f,
    const short* __restrict__ g, const short* __restrict__ hT,
    const short* __restrict__ WoT, const float* __restrict__ x,
    float* __restrict__ out) {
  extern __shared__ __align__(16) char smem[];
  const int b = blockIdx.y, q0 = blockIdx.x * 128;
  const int tid = threadIdx.x, w = tid >> 6, lane = tid & 63;
  const int l31 = lane & 31, hi = lane >> 5;

  bf16x8 fq[4];
  {
    const short* frow = f + ((long)b*4096 + q0 + w*32 + l31) * 64;
    #pragma unroll
    for (int ks = 0; ks < 4; ++ks) fq[ks] = *(const bf16x8*)(frow + ks*16 + hi*8);
  }

  f32x16 acc2[8] = {};     // [nc2] : n = nc2*32 + (g&3)+8*(g>>2)+4*hi, q = l31
  float rsq = 0.f;

  auto stage = [&](int buf, int kt) {   // 10 gload16 per wave per call
    const int k0 = kt * 64;
    short* gbuf = (short*)(smem + buf*8192);
    short* hbuf = (short*)(smem + 16384 + buf*32768);
    #pragma unroll
    for (int it = 0; it < 2; ++it) {          // g: 64 rows x 8 slots = 512 chunks
      int c = it*256 + w*64 + lane;
      int row = c >> 3, gslot = (c & 7) ^ (row & 7);
      gload16(g + ((long)b*1024 + k0 + row)*64 + gslot*8, gbuf + (it*256 + w*64)*8);
    }
    #pragma unroll
    for (int it = 0; it < 8; ++it) {          // hT: 256 rows x 8 slots = 2048 chunks
      int c = it*256 + w*64 + lane;
      int row = c >> 3, gslot = (c & 7) ^ (row & 7);
      gload16(hT + ((long)b*256 + row)*1024 + k0 + gslot*8, hbuf + (it*256 + w*64)*8);
    }
  };

  stage(0, 0);
  int cur = 0;
  for (int kt = 0; kt < 16; ++kt) {
    if (kt < 15) {
      stage(cur ^ 1, kt + 1);
      // wait only for CURRENT tile's 10 loads (issued last iter); next's 10 stay in flight
      asm volatile("s_waitcnt vmcnt(10)" ::: "memory");
    } else {
      asm volatile("s_waitcnt vmcnt(0)" ::: "memory");
    }
    __builtin_amdgcn_s_barrier();          // current buffer visible to all waves
    const char* gcur = (const char*)(smem + cur*8192);
    const char* hcur = (const char*)(smem + 16384 + cur*32768);
    // ---- QK^T (swapped) + exp + in-register P^T fragment assembly ----
    bf16x8 pa[4];
    #pragma unroll
    for (int kc2 = 0; kc2 < 2; ++kc2) {
      f32x16 s2 = {};
      #pragma unroll
      for (int ks = 0; ks < 4; ++ks) {
        int key = kc2*32 + l31;
        bf16x8 gb = *(const bf16x8*)(gcur + key*128 + (((ks*2 + hi) ^ (l31 & 7)) << 4));
        s2 = mfma32(gb, fq[ks], s2);
      }
      #pragma unroll
      for (int fh = 0; fh < 2; ++fh) {
        const int G = fh*8;
        float e0 = __expf(s2[G+0]), e1 = __expf(s2[G+1]);
        float e2 = __expf(s2[G+2]), e3 = __expf(s2[G+3]);
        float e4 = __expf(s2[G+4]), e5 = __expf(s2[G+5]);
        float e6 = __expf(s2[G+6]), e7 = __expf(s2[G+7]);
        rsq += ((e0 + e1) + (e2 + e3)) + ((e4 + e5) + (e6 + e7));
        unsigned a0 = cvtpk(e0, e1), a1 = cvtpk(e2, e3);
        unsigned b0 = cvtpk(e4, e5), b1 = cvtpk(e6, e7);
        asm volatile("v_permlane32_swap_b32 %0, %1" : "+v"(b0), "+v"(a0));
        asm volatile("v_permlane32_swap_b32 %0, %1" : "+v"(b1), "+v"(a1));
        union { unsigned u[4]; bf16x8 v; } pk;
        pk.u[0] = a0; pk.u[1] = a1; pk.u[2] = b0; pk.u[3] = b1;
        pa[kc2*2 + fh] = pk.v;
      }
    }
    // ---- PV (swapped), P from registers ----
    __builtin_amdgcn_s_setprio(1);
    #pragma unroll
    for (int ks = 0; ks < 4; ++ks) {
      #pragma unroll
      for (int nc2 = 0; nc2 < 8; ++nc2) {
        int n = nc2*32 + l31;
        bf16x8 hb = *(const bf16x8*)(hcur + n*128 + (((ks*2 + hi) ^ (l31 & 7)) << 4));
        acc2[nc2] = mfma32(hb, pa[ks], acc2[nc2]);
      }
    }
    __builtin_amdgcn_s_setprio(0);
    __builtin_amdgcn_s_barrier();          // all waves done reading cur before overwrite
    cur ^= 1;
  }
  // ---- normalize + assemble y^T B-frags in-register ----
  rsq += __shfl_xor(rsq, 32);
  float ri = 1.f / rsq;
  bf16x8 yB[16];
  #pragma unroll
  for (int nc2 = 0; nc2 < 8; ++nc2) {
    #pragma unroll
    for (int fh = 0; fh < 2; ++fh) {
      const int G = fh*8;
      unsigned a0 = cvtpk(acc2[nc2][G+0]*ri, acc2[nc2][G+1]*ri);
      unsigned a1 = cvtpk(acc2[nc2][G+2]*ri, acc2[nc2][G+3]*ri);
      unsigned b0 = cvtpk(acc2[nc2][G+4]*ri, acc2[nc2][G+5]*ri);
      unsigned b1 = cvtpk(acc2[nc2][G+6]*ri, acc2[nc2][G+7]*ri);
      asm volatile("v_permlane32_swap_b32 %0, %1" : "+v"(b0), "+v"(a0));
      asm volatile("v_permlane32_swap_b32 %0, %1" : "+v"(b1), "+v"(a1));
      union { unsigned u[4]; bf16x8 v; } pk;
      pk.u[0] = a0; pk.u[1] = a1; pk.u[2] = b0; pk.u[3] = b1;
      yB[nc2*2 + fh] = pk.v;
    }
  }
  // ---- out-GEMM: out[q][c] = sum_n Wo[n][c]*y[q][n] + x[q][c], register-only ----
  const long qrow = (long)b*4096 + q0 + w*32 + l31;
  const float* xrow = x + qrow*512;
  float* orow = out + qrow*512;
  for (int cc2 = 0; cc2 < 16; ++cc2) {
    f32x16 ao0 = {}, ao1 = {};
    #pragma unroll
    for (int ns2 = 0; ns2 < 8; ++ns2) {
      bf16x8 wo0 = *(const bf16x8*)(WoT + (cc2*32 + l31)*256 + (2*ns2  )*16 + hi*8);
      bf16x8 wo1 = *(const bf16x8*)(WoT + (cc2*32 + l31)*256 + (2*ns2+1)*16 + hi*8);
      ao0 = mfma32(wo0, yB[2*ns2  ], ao0);
      ao1 = mfma32(wo1, yB[2*ns2+1], ao1);
    }
    #pragma unroll
    for (int g2 = 0; g2 < 4; ++g2) {
      int c = cc2*32 + g2*8 + hi*4;
      float4 xv = *(const float4*)(xrow + c);
      float4 ov;
      ov.x = ao0[g2*4+0] + ao1[g2*4+0] + xv.x;
      ov.y = ao0[g2*4+1] + ao1[g2*4+1] + xv.y;
      ov.z = ao0[g2*4+2] + ao1[g2*4+2] + xv.z;
      ov.w = ao0[g2*4+3] + ao1[g2*4+3] + xv.w;
      *(float4*)(orow + c) = ov;
    }
  }
}

extern "C" void kernel_launch(void* const* d_in, const int* in_sizes, int n_in,
                              void* d_out, int out_size, void* d_ws, size_t ws_size,
                              hipStream_t stream) {
  const float* x  = (const float*)d_in[0];
  const float* Wf = (const float*)d_in[1];
  const float* Wg = (const float*)d_in[2];
  const float* Wh = (const float*)d_in[3];
  const float* Wo = (const float*)d_in[4];
  float* out = (float*)d_out;

  // workspace carve-up (bf16 elements)
  short* xp  = (short*)d_ws;                    // [16*1024, 512]
  short* fb  = xp  + (long)16*1024*512;         // [65536, 64]
  short* gb  = fb  + (long)65536*64;            // [16384, 64]
  short* hb  = gb  + (long)16384*64;            // [16384, 256]
  short* hTb = hb  + (long)16384*256;           // [16*256, 1024]
  short* WfT = hTb + (long)16*256*1024;         // [64, 512]
  short* WgT = WfT + 64*512;
  short* WhT = WgT + 64*512;
  short* WoT = WhT + 256*512;

  hipFuncSetAttribute((const void*)attn_kernel,
                      hipFuncAttributeMaxDynamicSharedMemorySize, 81920);

  prep_weights<<<1536, 256, 0, stream>>>(Wf, Wg, Wh, Wo, WfT, WgT, WhT, WoT);
  gemm_k512<true , true ><<<dim3(512, 1), 256, 0, stream>>>((const void*)x,  WfT, fb, 64,  xp);
  gemm_k512<false, false><<<dim3(128, 1), 256, 0, stream>>>((const void*)xp, WgT, gb, 64,  nullptr);
  gemm_k512<false, false><<<dim3(128, 4), 256, 0, stream>>>((const void*)xp, WhT, hb, 256, nullptr);
  transpose_h <<<dim3(16, 4, 16), 256, 0, stream>>>(hb, hTb);
  attn_kernel <<<dim3(32, 16), 256, 81920, stream>>>(fb, gb, hTb, WoT, x, out);
}